// Round 14
// baseline (406.463 us; speedup 1.0000x reference)
//
#include <hip/hip_runtime.h>

#define D 64
#define ROWTILE 32
#define XPAD 68    // LDS row pad (floats); staging showed 0 bank conflicts in R7
#define CHUNK 4096 // edges per bucket_scatter block
#define NBMAX 512  // bucket array capacity (actual nbk = ceil(N/256))

// ---------------------------------------------------------------------------
// Detect whether edge_index is stored as int64 (odd int32 words all zero,
// since node ids < 2^31) or int32. Writes 1 (int64) / 0 (int32) to *flag.
// ---------------------------------------------------------------------------
__global__ void detect_kernel(const void* __restrict__ e, int* __restrict__ flag) {
    if (threadIdx.x == 0 && blockIdx.x == 0) {
        const int* p = (const int*)e;
        int is64 = 1;
        for (int i = 1; i < 64; i += 2) {
            if (p[i] != 0) { is64 = 0; break; }
        }
        *flag = is64;
    }
}

__device__ __forceinline__ void load_edge(const void* __restrict__ eidx, int is64,
                                          int e, int nE, int& src, int& dst) {
    if (is64) {
        const long long* p = (const long long*)eidx;
        src = (int)p[e];
        dst = (int)p[nE + e];
    } else {
        const int* p = (const int*)eidx;
        src = p[e];
        dst = p[nE + e];
    }
}

// ---------------------------------------------------------------------------
// Per-node histogram of dst
// ---------------------------------------------------------------------------
__global__ __launch_bounds__(256) void hist_kernel(
    const void* __restrict__ eidx, const int* __restrict__ flag,
    int* __restrict__ count, int nE)
{
    const int is64 = *flag;
    int e = blockIdx.x * 256 + threadIdx.x;
    if (e >= nE) return;
    int src, dst;
    load_edge(eidx, is64, e, nE, src, dst);
    atomicAdd(&count[dst], 1);
}

// per-block exclusive scan of count -> offs, block totals -> bsum
__global__ __launch_bounds__(256) void scan1_kernel(
    const int* __restrict__ count, int* __restrict__ offs,
    int* __restrict__ bsum, int N)
{
    __shared__ int tmp[256];
    const int tid = threadIdx.x;
    const int i = blockIdx.x * 256 + tid;
    int v = (i < N) ? count[i] : 0;
    tmp[tid] = v;
    __syncthreads();
#pragma unroll
    for (int off = 1; off < 256; off <<= 1) {
        int t = (tid >= off) ? tmp[tid - off] : 0;
        __syncthreads();
        tmp[tid] += t;
        __syncthreads();
    }
    int incl = tmp[tid];
    if (i < N) offs[i] = incl - v;          // exclusive
    if (tid == 255) bsum[blockIdx.x] = incl; // block total
}

// single-block exclusive scan of block sums (supports up to 1024 blocks)
__global__ __launch_bounds__(1024) void scan2_kernel(int* __restrict__ bsum, int nblk)
{
    __shared__ int tmp[1024];
    const int tid = threadIdx.x;
    int v = (tid < nblk) ? bsum[tid] : 0;
    tmp[tid] = v;
    __syncthreads();
#pragma unroll
    for (int off = 1; off < 1024; off <<= 1) {
        int t = (tid >= off) ? tmp[tid - off] : 0;
        __syncthreads();
        tmp[tid] += t;
        __syncthreads();
    }
    if (tid < nblk) bsum[tid] = tmp[tid] - v; // exclusive
}

// add block offsets; offs[N] = E
__global__ __launch_bounds__(256) void scan3_kernel(
    int* __restrict__ offs, const int* __restrict__ bsum, int N, int E)
{
    const int i = blockIdx.x * 256 + threadIdx.x;
    if (i < N) offs[i] += bsum[blockIdx.x];
    if (i == 0) offs[N] = E;
}

// ---------------------------------------------------------------------------
// Bucket scatter: partition edges into dst-buckets (bucket = dst>>8) with
// LDS staging so global writes are coalesced runs, not random 4B stores.
// ---------------------------------------------------------------------------
__global__ __launch_bounds__(256) void bucket_scatter_kernel(
    const void* __restrict__ eidx, const int* __restrict__ flag,
    const int* __restrict__ offs, int* __restrict__ gbcur,
    uint2* __restrict__ ebuk, int nE, int N, int nbk)
{
    __shared__ int bcnt[NBMAX];
    __shared__ int boffs[NBMAX];
    __shared__ int brun[NBMAX];
    __shared__ int gbase[NBMAX];
    __shared__ int bstart[NBMAX];
    __shared__ int ps[256];
    __shared__ uint2 staged[CHUNK];

    const int is64 = *flag;
    const int tid = threadIdx.x;
    const int e0 = blockIdx.x * CHUNK;
    const int ec = min(CHUNK, nE - e0);

    for (int i = tid; i < NBMAX; i += 256) { bcnt[i] = 0; brun[i] = 0; }
    for (int i = tid; i < nbk; i += 256) bstart[i] = offs[i << 8];
    __syncthreads();

    // pass A: count buckets (edges re-read in pass B; L2-hot)
#pragma unroll
    for (int j = 0; j < CHUNK / 256; ++j) {
        const int i = j * 256 + tid;
        if (i < ec) {
            int s, d;
            load_edge(eidx, is64, e0 + i, nE, s, d);
            atomicAdd(&bcnt[d >> 8], 1);
        }
    }
    __syncthreads();

    // exclusive scan of bcnt[0..NBMAX): 2 entries per thread + Hillis-Steele
    const int c0 = bcnt[2 * tid], c1 = bcnt[2 * tid + 1];
    ps[tid] = c0 + c1;
    __syncthreads();
#pragma unroll
    for (int off = 1; off < 256; off <<= 1) {
        int t = (tid >= off) ? ps[tid - off] : 0;
        __syncthreads();
        ps[tid] += t;
        __syncthreads();
    }
    const int pexcl = ps[tid] - (c0 + c1);
    boffs[2 * tid]     = pexcl;
    boffs[2 * tid + 1] = pexcl + c0;
    // reserve this block's run in each bucket's global region
    if (c0 > 0) gbase[2 * tid]     = atomicAdd(&gbcur[2 * tid], c0);
    if (c1 > 0) gbase[2 * tid + 1] = atomicAdd(&gbcur[2 * tid + 1], c1);
    __syncthreads();

    // pass B: stage bucket-sorted into LDS
#pragma unroll
    for (int j = 0; j < CHUNK / 256; ++j) {
        const int i = j * 256 + tid;
        if (i < ec) {
            int s, d;
            load_edge(eidx, is64, e0 + i, nE, s, d);
            const int b = d >> 8;
            const int p = boffs[b] + atomicAdd(&brun[b], 1);
            staged[p] = make_uint2((unsigned)s, (unsigned)d);
        }
    }
    __syncthreads();

    // flush: consecutive staged entries of a bucket -> consecutive global slots
    for (int i = tid; i < ec; i += 256) {
        const uint2 ent = staged[i];
        const int b = (int)(ent.y >> 8);
        const int pos = bstart[b] + gbase[b] + (i - boffs[b]);
        ebuk[pos] = ent;
    }
}

// ---------------------------------------------------------------------------
// Bucket -> exact CSR: one block per bucket; LDS cursors from offs; writes
// land in the bucket's dense CSR range (single XCD -> L2 write-combining).
// ---------------------------------------------------------------------------
__global__ __launch_bounds__(256) void bucket_csr_kernel(
    const uint2* __restrict__ ebuk, const int* __restrict__ offs,
    int* __restrict__ ssrc, int N)
{
    __shared__ int lcur[256];
    const int b  = blockIdx.x;
    const int n0 = b << 8;
    const int nn = min(256, N - n0);
    const int tid = threadIdx.x;
    const int bs = offs[n0];
    const int be = offs[min(n0 + 256, N)];
    if (tid < nn) lcur[tid] = offs[n0 + tid];
    __syncthreads();
    for (int i = bs + tid; i < be; i += 256) {
        const uint2 ent = ebuk[i];
        const int pos = atomicAdd(&lcur[(int)ent.y - n0], 1);
        ssrc[pos] = (int)ent.x;
    }
}

// ---------------------------------------------------------------------------
// Segmented gather-sum: aggr[n] = sum over sorted in-edges of feat[src].
// 16 lanes per node (float4 chunks), 16 nodes per block. No f32 atomics.
// ---------------------------------------------------------------------------
__global__ __launch_bounds__(256) void gather_aggr_kernel(
    const float* __restrict__ feat, const int* __restrict__ ssrc,
    const int* __restrict__ offs, float* __restrict__ aggr, int N)
{
    const int g = threadIdx.x >> 4;   // node group within block
    const int c = threadIdx.x & 15;   // float4 chunk
    const int n = blockIdx.x * 16 + g;
    if (n >= N) return;
    const int e0 = offs[n], e1 = offs[n + 1];
    float4 acc = make_float4(0.f, 0.f, 0.f, 0.f);
#pragma unroll 4
    for (int e = e0; e < e1; ++e) {
        int s = ssrc[e];
        float4 v = *(const float4*)(feat + (long long)s * D + c * 4);
        acc.x += v.x; acc.y += v.y; acc.z += v.z; acc.w += v.w;
    }
    *(float4*)(aggr + (long long)n * D + c * 4) = acc;
}

// ---------------------------------------------------------------------------
// Fused linear: out[i][d] = relu( aggr[i]@Wrel + in[i]@Wroot + b )[d]
// MATRIX-SPLIT across waves (role 0 = Wroot/x, role 1 = Wrel/aggr), rows
// staged coalesced into LDS, partials exchanged via LDS.
// ONE TILE PER BLOCK (grid = ntiles): R13 showed grid-stride over 3.05
// tiles/block left 18% occupancy + 25% straggler imbalance (blocks with 4
// tiles vs 3). One tile/block removes the loop-carried barriers and lets
// 5 LDS-limited blocks/CU stream independently.
// ---------------------------------------------------------------------------
template <bool WRITE_OUT, bool WRITE_PART>
__global__ __launch_bounds__(256, 3) void linear_relu_kernel(
    const float* __restrict__ in, const float* __restrict__ aggr,
    const float* __restrict__ Wrel, const float* __restrict__ Wroot,
    const float* __restrict__ bias,
    float* __restrict__ out, float* __restrict__ acc_out, int N)
{
    __shared__ float xs[ROWTILE][XPAD];      // staged rows of in
    __shared__ float gs[ROWTILE][XPAD];      // staged rows of aggr
    __shared__ float pb[2][16][XPAD];        // rel partials, per pair
    __shared__ float red[4][D];

    const int tid  = threadIdx.x;
    const int lane = tid & 63;
    const int wid  = tid >> 6;
    const int pair = wid >> 1;     // 0,1
    const int role = wid & 1;      // 0 = root (finisher), 1 = rel

    float wv[D];
    {
        const float* W = role ? Wrel : Wroot;
#pragma unroll
        for (int k = 0; k < D; ++k) wv[k] = W[k * D + lane];
    }
    const float bv = bias[lane];

    const long long rowbase = (long long)blockIdx.x * ROWTILE;
    // ---- coalesced stage: 32 rows x 64 floats x 2 arrays ----
#pragma unroll
    for (int it = 0; it < 2; ++it) {
        const int i = it * 256 + tid;        // 0..511
        const int r = i >> 4;                // tile row
        const int c = i & 15;                // float4 chunk
        long long row = rowbase + r;
        if (row >= N) row = N - 1;           // clamp; guarded at write
        const long long off = row * D + c * 4;
        *(float4*)&xs[r][c * 4] = *(const float4*)(in + off);
        *(float4*)&gs[r][c * 4] = *(const float4*)(aggr + off);
    }
    __syncthreads();
    // ---- each wave: 16 rows' partial dots from its tile ----
    float part[16];
#pragma unroll
    for (int g = 0; g < 4; ++g) {
        const int r0 = pair * 16 + g * 4;
        float a0 = 0.f, a1 = 0.f, a2 = 0.f, a3 = 0.f;
        const float (*src)[XPAD] = role ? gs : xs;
#pragma unroll
        for (int k4 = 0; k4 < D / 4; ++k4) {
            float4 f0 = *(const float4*)&src[r0 + 0][k4 * 4];  // LDS broadcast
            float4 f1 = *(const float4*)&src[r0 + 1][k4 * 4];
            float4 f2 = *(const float4*)&src[r0 + 2][k4 * 4];
            float4 f3 = *(const float4*)&src[r0 + 3][k4 * 4];
            const float w0 = wv[4 * k4 + 0], w1 = wv[4 * k4 + 1];
            const float w2 = wv[4 * k4 + 2], w3 = wv[4 * k4 + 3];
            a0 = fmaf(f0.x, w0, a0); a0 = fmaf(f0.y, w1, a0);
            a0 = fmaf(f0.z, w2, a0); a0 = fmaf(f0.w, w3, a0);
            a1 = fmaf(f1.x, w0, a1); a1 = fmaf(f1.y, w1, a1);
            a1 = fmaf(f1.z, w2, a1); a1 = fmaf(f1.w, w3, a1);
            a2 = fmaf(f2.x, w0, a2); a2 = fmaf(f2.y, w1, a2);
            a2 = fmaf(f2.z, w2, a2); a2 = fmaf(f2.w, w3, a2);
            a3 = fmaf(f3.x, w0, a3); a3 = fmaf(f3.y, w1, a3);
            a3 = fmaf(f3.z, w2, a3); a3 = fmaf(f3.w, w3, a3);
        }
        part[g * 4 + 0] = a0; part[g * 4 + 1] = a1;
        part[g * 4 + 2] = a2; part[g * 4 + 3] = a3;
    }
    // ---- rel waves publish partials ----
    if (role == 1) {
#pragma unroll
        for (int r = 0; r < 16; ++r) pb[pair][r][lane] = part[r];
    }
    __syncthreads();
    // ---- root waves finish: add, bias, relu, write ----
    float csum = 0.f;
    if (role == 0) {
#pragma unroll
        for (int r = 0; r < 16; ++r) {
            const long long grow = rowbase + pair * 16 + r;
            const float o = fmaxf(part[r] + pb[pair][r][lane] + bv, 0.f);
            if (grow < N) {
                if (WRITE_OUT) out[grow * D + lane] = o;
                if (WRITE_PART) csum += o;
            }
        }
    }

    if (WRITE_PART) {
        __syncthreads();
        red[wid][lane] = csum;
        __syncthreads();
        if (tid < D) {
            float s = red[0][tid] + red[1][tid] + red[2][tid] + red[3][tid];
            unsafeAtomicAdd(&acc_out[tid], s);
        }
    }
}

// ---------------------------------------------------------------------------
// Final: acc[64] -> mean -> [64] @ Wc[64,2] + bc -> out[2]
// ---------------------------------------------------------------------------
__global__ void final_kernel(const float* __restrict__ acc,
                             const float* __restrict__ Wc, const float* __restrict__ bc,
                             float* __restrict__ out, float invN)
{
    const int lane = threadIdx.x;  // 64 threads
    float m  = acc[lane] * invN;
    float o0 = m * Wc[lane * 2 + 0];
    float o1 = m * Wc[lane * 2 + 1];
#pragma unroll
    for (int off = 32; off > 0; off >>= 1) {
        o0 += __shfl_down(o0, off);
        o1 += __shfl_down(o1, off);
    }
    if (lane == 0) {
        out[0] = o0 + bc[0];
        out[1] = o1 + bc[1];
    }
}

extern "C" void kernel_launch(void* const* d_in, const int* in_sizes, int n_in,
                              void* d_out, int out_size, void* d_ws, size_t ws_size,
                              hipStream_t stream)
{
    const float* x       = (const float*)d_in[0];
    const void*  eidx    = d_in[1];
    const float* W1_rel  = (const float*)d_in[2];
    const float* W1_root = (const float*)d_in[3];
    const float* b1      = (const float*)d_in[4];
    const float* W2_rel  = (const float*)d_in[5];
    const float* W2_root = (const float*)d_in[6];
    const float* b2      = (const float*)d_in[7];
    const float* Wc      = (const float*)d_in[8];
    const float* bc      = (const float*)d_in[9];
    float* out = (float*)d_out;

    const int N = in_sizes[0] / D;
    const int E = in_sizes[1] / 2;

    auto align256 = [](size_t v) { return (v + 255) & ~(size_t)255; };

    char* p = (char*)d_ws;
    const size_t featBytes = align256((size_t)N * D * sizeof(float));
    float* aggr   = (float*)p; p += featBytes;
    float* h1     = (float*)p; p += featBytes;
    float* acc    = (float*)p; p += align256((size_t)D * sizeof(float));
    int*   count  = (int*)p;   p += align256((size_t)N * sizeof(int));
    int*   offs   = (int*)p;   p += align256(((size_t)N + 1) * sizeof(int));
    int*   bsum   = (int*)p;   p += align256((size_t)1024 * sizeof(int));
    int*   gbcur  = (int*)p;   p += align256((size_t)NBMAX * sizeof(int));
    int*   ssrc   = (int*)p;   p += align256((size_t)E * sizeof(int));
    uint2* ebuk   = (uint2*)p; p += align256((size_t)E * sizeof(uint2));
    int*   flag   = (int*)p;

    const int eblocks = (E + 255) / 256;
    const int nblk    = (N + 255) / 256;   // scan blocks (must be <= 1024)
    const int nbk     = (N + 255) >> 8;    // buckets of 256 nodes (= nblk)
    const int cblocks = (E + CHUNK - 1) / CHUNK;
    const int ltiles  = (N + ROWTILE - 1) / ROWTILE;  // one tile per block

    // ---- CSR build (once, reused by both layers) ----
    detect_kernel<<<1, 64, 0, stream>>>(eidx, flag);
    hipMemsetAsync(count, 0, (size_t)N * sizeof(int), stream);
    hipMemsetAsync(acc, 0, (size_t)D * sizeof(float), stream);
    hipMemsetAsync(gbcur, 0, (size_t)NBMAX * sizeof(int), stream);
    hist_kernel<<<eblocks, 256, 0, stream>>>(eidx, flag, count, E);
    scan1_kernel<<<nblk, 256, 0, stream>>>(count, offs, bsum, N);
    scan2_kernel<<<1, 1024, 0, stream>>>(bsum, nblk);
    scan3_kernel<<<nblk, 256, 0, stream>>>(offs, bsum, N, E);
    bucket_scatter_kernel<<<cblocks, 256, 0, stream>>>(
        eidx, flag, offs, gbcur, ebuk, E, N, nbk);
    bucket_csr_kernel<<<nbk, 256, 0, stream>>>(ebuk, offs, ssrc, N);

    const int ablocks = (N + 15) / 16;

    // ---- layer 1 ----
    gather_aggr_kernel<<<ablocks, 256, 0, stream>>>(x, ssrc, offs, aggr, N);
    linear_relu_kernel<true, false><<<ltiles, 256, 0, stream>>>(
        x, aggr, W1_rel, W1_root, b1, h1, nullptr, N);

    // ---- layer 2 ----
    gather_aggr_kernel<<<ablocks, 256, 0, stream>>>(h1, ssrc, offs, aggr, N);
    linear_relu_kernel<false, true><<<ltiles, 256, 0, stream>>>(
        h1, aggr, W2_rel, W2_root, b2, nullptr, acc, N);

    // ---- head ----
    final_kernel<<<1, 64, 0, stream>>>(acc, Wc, bc, out, 1.0f / (float)N);
}

// Round 15
// 352.767 us; speedup vs baseline: 1.1522x; 1.1522x over previous
//
#include <hip/hip_runtime.h>

#define D 64
#define ROWTILE 32
#define XPAD 68    // LDS row pad (floats); 0 bank conflicts measured (R7/R13)
#define TPB_TILES 5 // tiles per linear block (f/c model: f~4.7us, c~3.2us)
#define CHUNK 4096 // edges per bucket_scatter block
#define NBMAX 512  // bucket array capacity (actual nbk = ceil(N/256))

// ---------------------------------------------------------------------------
// Detect whether edge_index is stored as int64 (odd int32 words all zero,
// since node ids < 2^31) or int32. Writes 1 (int64) / 0 (int32) to *flag.
// ---------------------------------------------------------------------------
__global__ void detect_kernel(const void* __restrict__ e, int* __restrict__ flag) {
    if (threadIdx.x == 0 && blockIdx.x == 0) {
        const int* p = (const int*)e;
        int is64 = 1;
        for (int i = 1; i < 64; i += 2) {
            if (p[i] != 0) { is64 = 0; break; }
        }
        *flag = is64;
    }
}

__device__ __forceinline__ void load_edge(const void* __restrict__ eidx, int is64,
                                          int e, int nE, int& src, int& dst) {
    if (is64) {
        const long long* p = (const long long*)eidx;
        src = (int)p[e];
        dst = (int)p[nE + e];
    } else {
        const int* p = (const int*)eidx;
        src = p[e];
        dst = p[nE + e];
    }
}

// ---------------------------------------------------------------------------
// Per-node histogram of dst
// ---------------------------------------------------------------------------
__global__ __launch_bounds__(256) void hist_kernel(
    const void* __restrict__ eidx, const int* __restrict__ flag,
    int* __restrict__ count, int nE)
{
    const int is64 = *flag;
    int e = blockIdx.x * 256 + threadIdx.x;
    if (e >= nE) return;
    int src, dst;
    load_edge(eidx, is64, e, nE, src, dst);
    atomicAdd(&count[dst], 1);
}

// per-block exclusive scan of count -> offs, block totals -> bsum
__global__ __launch_bounds__(256) void scan1_kernel(
    const int* __restrict__ count, int* __restrict__ offs,
    int* __restrict__ bsum, int N)
{
    __shared__ int tmp[256];
    const int tid = threadIdx.x;
    const int i = blockIdx.x * 256 + tid;
    int v = (i < N) ? count[i] : 0;
    tmp[tid] = v;
    __syncthreads();
#pragma unroll
    for (int off = 1; off < 256; off <<= 1) {
        int t = (tid >= off) ? tmp[tid - off] : 0;
        __syncthreads();
        tmp[tid] += t;
        __syncthreads();
    }
    int incl = tmp[tid];
    if (i < N) offs[i] = incl - v;          // exclusive
    if (tid == 255) bsum[blockIdx.x] = incl; // block total
}

// single-block exclusive scan of block sums (supports up to 1024 blocks)
__global__ __launch_bounds__(1024) void scan2_kernel(int* __restrict__ bsum, int nblk)
{
    __shared__ int tmp[1024];
    const int tid = threadIdx.x;
    int v = (tid < nblk) ? bsum[tid] : 0;
    tmp[tid] = v;
    __syncthreads();
#pragma unroll
    for (int off = 1; off < 1024; off <<= 1) {
        int t = (tid >= off) ? tmp[tid - off] : 0;
        __syncthreads();
        tmp[tid] += t;
        __syncthreads();
    }
    if (tid < nblk) bsum[tid] = tmp[tid] - v; // exclusive
}

// add block offsets; offs[N] = E
__global__ __launch_bounds__(256) void scan3_kernel(
    int* __restrict__ offs, const int* __restrict__ bsum, int N, int E)
{
    const int i = blockIdx.x * 256 + threadIdx.x;
    if (i < N) offs[i] += bsum[blockIdx.x];
    if (i == 0) offs[N] = E;
}

// ---------------------------------------------------------------------------
// Bucket scatter: partition edges into dst-buckets (bucket = dst>>8) with
// LDS staging so global writes are coalesced runs, not random 4B stores.
// ---------------------------------------------------------------------------
__global__ __launch_bounds__(256) void bucket_scatter_kernel(
    const void* __restrict__ eidx, const int* __restrict__ flag,
    const int* __restrict__ offs, int* __restrict__ gbcur,
    uint2* __restrict__ ebuk, int nE, int N, int nbk)
{
    __shared__ int bcnt[NBMAX];
    __shared__ int boffs[NBMAX];
    __shared__ int brun[NBMAX];
    __shared__ int gbase[NBMAX];
    __shared__ int bstart[NBMAX];
    __shared__ int ps[256];
    __shared__ uint2 staged[CHUNK];

    const int is64 = *flag;
    const int tid = threadIdx.x;
    const int e0 = blockIdx.x * CHUNK;
    const int ec = min(CHUNK, nE - e0);

    for (int i = tid; i < NBMAX; i += 256) { bcnt[i] = 0; brun[i] = 0; }
    for (int i = tid; i < nbk; i += 256) bstart[i] = offs[i << 8];
    __syncthreads();

    // pass A: count buckets (edges re-read in pass B; L2-hot)
#pragma unroll
    for (int j = 0; j < CHUNK / 256; ++j) {
        const int i = j * 256 + tid;
        if (i < ec) {
            int s, d;
            load_edge(eidx, is64, e0 + i, nE, s, d);
            atomicAdd(&bcnt[d >> 8], 1);
        }
    }
    __syncthreads();

    // exclusive scan of bcnt[0..NBMAX): 2 entries per thread + Hillis-Steele
    const int c0 = bcnt[2 * tid], c1 = bcnt[2 * tid + 1];
    ps[tid] = c0 + c1;
    __syncthreads();
#pragma unroll
    for (int off = 1; off < 256; off <<= 1) {
        int t = (tid >= off) ? ps[tid - off] : 0;
        __syncthreads();
        ps[tid] += t;
        __syncthreads();
    }
    const int pexcl = ps[tid] - (c0 + c1);
    boffs[2 * tid]     = pexcl;
    boffs[2 * tid + 1] = pexcl + c0;
    // reserve this block's run in each bucket's global region
    if (c0 > 0) gbase[2 * tid]     = atomicAdd(&gbcur[2 * tid], c0);
    if (c1 > 0) gbase[2 * tid + 1] = atomicAdd(&gbcur[2 * tid + 1], c1);
    __syncthreads();

    // pass B: stage bucket-sorted into LDS
#pragma unroll
    for (int j = 0; j < CHUNK / 256; ++j) {
        const int i = j * 256 + tid;
        if (i < ec) {
            int s, d;
            load_edge(eidx, is64, e0 + i, nE, s, d);
            const int b = d >> 8;
            const int p = boffs[b] + atomicAdd(&brun[b], 1);
            staged[p] = make_uint2((unsigned)s, (unsigned)d);
        }
    }
    __syncthreads();

    // flush: consecutive staged entries of a bucket -> consecutive global slots
    for (int i = tid; i < ec; i += 256) {
        const uint2 ent = staged[i];
        const int b = (int)(ent.y >> 8);
        const int pos = bstart[b] + gbase[b] + (i - boffs[b]);
        ebuk[pos] = ent;
    }
}

// ---------------------------------------------------------------------------
// Bucket -> exact CSR: one block per bucket; LDS cursors from offs; writes
// land in the bucket's dense CSR range (single XCD -> L2 write-combining).
// ---------------------------------------------------------------------------
__global__ __launch_bounds__(256) void bucket_csr_kernel(
    const uint2* __restrict__ ebuk, const int* __restrict__ offs,
    int* __restrict__ ssrc, int N)
{
    __shared__ int lcur[256];
    const int b  = blockIdx.x;
    const int n0 = b << 8;
    const int nn = min(256, N - n0);
    const int tid = threadIdx.x;
    const int bs = offs[n0];
    const int be = offs[min(n0 + 256, N)];
    if (tid < nn) lcur[tid] = offs[n0 + tid];
    __syncthreads();
    for (int i = bs + tid; i < be; i += 256) {
        const uint2 ent = ebuk[i];
        const int pos = atomicAdd(&lcur[(int)ent.y - n0], 1);
        ssrc[pos] = (int)ent.x;
    }
}

// ---------------------------------------------------------------------------
// Segmented gather-sum: aggr[n] = sum over sorted in-edges of feat[src].
// ---------------------------------------------------------------------------
__global__ __launch_bounds__(256) void gather_aggr_kernel(
    const float* __restrict__ feat, const int* __restrict__ ssrc,
    const int* __restrict__ offs, float* __restrict__ aggr, int N)
{
    const int g = threadIdx.x >> 4;   // node group within block
    const int c = threadIdx.x & 15;   // float4 chunk
    const int n = blockIdx.x * 16 + g;
    if (n >= N) return;
    const int e0 = offs[n], e1 = offs[n + 1];
    float4 acc = make_float4(0.f, 0.f, 0.f, 0.f);
#pragma unroll 4
    for (int e = e0; e < e1; ++e) {
        int s = ssrc[e];
        float4 v = *(const float4*)(feat + (long long)s * D + c * 4);
        acc.x += v.x; acc.y += v.y; acc.z += v.z; acc.w += v.w;
    }
    *(float4*)(aggr + (long long)n * D + c * 4) = acc;
}

// ---------------------------------------------------------------------------
// Fused linear v3 (R15): matrix-split waves + balanced 5 tiles/block +
// LDS-coalesced weight preload (aliased region) + register prefetch.
// ---------------------------------------------------------------------------
template <bool WRITE_OUT, bool WRITE_PART>
__global__ __launch_bounds__(256, 3) void linear_relu_kernel(
    const float* __restrict__ in, const float* __restrict__ aggr,
    const float* __restrict__ Wrel, const float* __restrict__ Wroot,
    const float* __restrict__ bias,
    float* __restrict__ out, float* __restrict__ acc_out, int N, int ntiles)
{
    __shared__ float smem[8192];   // 32 KB, dual-purpose

    const int tid  = threadIdx.x;
    const int lane = tid & 63;
    const int wid  = tid >> 6;
    const int pair = wid >> 1;     // 0,1
    const int role = wid & 1;      // 0 = root (finisher), 1 = rel

    // ---- phase 1: stage Wroot|Wrel into LDS (coalesced float4) ----
#pragma unroll
    for (int it = 0; it < 8; ++it) {
        const int j = it * 256 + tid;              // float4 index 0..2047
        const float* Wsrc = (j < 1024) ? Wroot : Wrel;
        const int jj = (j < 1024) ? j : j - 1024;
        *(float4*)&smem[j * 4] = *(const float4*)&Wsrc[jj * 4];
    }
    __syncthreads();
    // extract per-lane column (stride-64 LDS reads: 2 lanes/bank = free)
    float wv[D];
    {
        const int base = role ? 4096 : 0;
#pragma unroll
        for (int k = 0; k < D; ++k) wv[k] = smem[base + k * D + lane];
    }
    const float bv = bias[lane];
    __syncthreads();   // weights in regs; smem now reusable

    // ---- phase 2: alias tile buffers onto smem ----
    float (*xs)[XPAD] = (float(*)[XPAD])&smem[0];                  // [32][68]
    float (*gs)[XPAD] = (float(*)[XPAD])&smem[ROWTILE * XPAD];     // [32][68]
    float (*pb)[XPAD] = (float(*)[XPAD])&smem[2 * ROWTILE * XPAD]; // [32][68]
    float* red        = &smem[3 * ROWTILE * XPAD];                 // [256]

    const int tile0 = blockIdx.x * TPB_TILES;
    float csum = 0.f;
    float4 px0, px1, pg0, pg1;     // prefetch registers

    // prologue: prefetch tile0
    {
        const int tl = (tile0 < ntiles) ? tile0 : (ntiles - 1);
        const long long rowbase = (long long)tl * ROWTILE;
        {
            const int r = tid >> 4, c = tid & 15;
            long long row = rowbase + r; if (row >= N) row = N - 1;
            const long long off = row * D + c * 4;
            px0 = *(const float4*)(in + off);
            pg0 = *(const float4*)(aggr + off);
        }
        {
            const int i = 256 + tid;
            const int r = i >> 4, c = i & 15;
            long long row = rowbase + r; if (row >= N) row = N - 1;
            const long long off = row * D + c * 4;
            px1 = *(const float4*)(in + off);
            pg1 = *(const float4*)(aggr + off);
        }
    }

    for (int t = 0; t < TPB_TILES; ++t) {
        const int tile = tile0 + t;
        if (tile >= ntiles) break;
        const long long rowbase = (long long)tile * ROWTILE;

        // ---- write prefetched regs to LDS ----
        {
            const int r0 = tid >> 4, c0 = tid & 15;
            *(float4*)&xs[r0][c0 * 4] = px0;
            *(float4*)&gs[r0][c0 * 4] = pg0;
            const int i1 = 256 + tid;
            const int r1 = i1 >> 4, c1 = i1 & 15;
            *(float4*)&xs[r1][c1 * 4] = px1;
            *(float4*)&gs[r1][c1 * 4] = pg1;
        }
        __syncthreads();

        // ---- prefetch tile t+1 (hides under compute) ----
        if (t + 1 < TPB_TILES && tile + 1 < ntiles) {
            const long long nrb = (long long)(tile + 1) * ROWTILE;
            {
                const int r = tid >> 4, c = tid & 15;
                long long row = nrb + r; if (row >= N) row = N - 1;
                const long long off = row * D + c * 4;
                px0 = *(const float4*)(in + off);
                pg0 = *(const float4*)(aggr + off);
            }
            {
                const int i = 256 + tid;
                const int r = i >> 4, c = i & 15;
                long long row = nrb + r; if (row >= N) row = N - 1;
                const long long off = row * D + c * 4;
                px1 = *(const float4*)(in + off);
                pg1 = *(const float4*)(aggr + off);
            }
        }

        // ---- compute partials for this wave's 16 rows ----
        float part[16];
#pragma unroll
        for (int g = 0; g < 4; ++g) {
            const int r0 = pair * 16 + g * 4;
            float a0 = 0.f, a1 = 0.f, a2 = 0.f, a3 = 0.f;
            const float (*src)[XPAD] = role ? gs : xs;
#pragma unroll
            for (int k4 = 0; k4 < D / 4; ++k4) {
                float4 f0 = *(const float4*)&src[r0 + 0][k4 * 4];  // LDS broadcast
                float4 f1 = *(const float4*)&src[r0 + 1][k4 * 4];
                float4 f2 = *(const float4*)&src[r0 + 2][k4 * 4];
                float4 f3 = *(const float4*)&src[r0 + 3][k4 * 4];
                const float w0 = wv[4 * k4 + 0], w1 = wv[4 * k4 + 1];
                const float w2 = wv[4 * k4 + 2], w3 = wv[4 * k4 + 3];
                a0 = fmaf(f0.x, w0, a0); a0 = fmaf(f0.y, w1, a0);
                a0 = fmaf(f0.z, w2, a0); a0 = fmaf(f0.w, w3, a0);
                a1 = fmaf(f1.x, w0, a1); a1 = fmaf(f1.y, w1, a1);
                a1 = fmaf(f1.z, w2, a1); a1 = fmaf(f1.w, w3, a1);
                a2 = fmaf(f2.x, w0, a2); a2 = fmaf(f2.y, w1, a2);
                a2 = fmaf(f2.z, w2, a2); a2 = fmaf(f2.w, w3, a2);
                a3 = fmaf(f3.x, w0, a3); a3 = fmaf(f3.y, w1, a3);
                a3 = fmaf(f3.z, w2, a3); a3 = fmaf(f3.w, w3, a3);
            }
            part[g * 4 + 0] = a0; part[g * 4 + 1] = a1;
            part[g * 4 + 2] = a2; part[g * 4 + 3] = a3;
        }
        // rel waves publish partials
        if (role == 1) {
#pragma unroll
            for (int r = 0; r < 16; ++r) pb[pair * 16 + r][lane] = part[r];
        }
        __syncthreads();
        // root waves finish (reads pb only; xs/gs free for next iteration)
        if (role == 0) {
#pragma unroll
            for (int r = 0; r < 16; ++r) {
                const long long grow = rowbase + pair * 16 + r;
                const float o = fmaxf(part[r] + pb[pair * 16 + r][lane] + bv, 0.f);
                if (grow < N) {
                    if (WRITE_OUT) out[grow * D + lane] = o;
                    if (WRITE_PART) csum += o;
                }
            }
        }
    }

    if (WRITE_PART) {
        __syncthreads();
        red[wid * D + lane] = csum;
        __syncthreads();
        if (tid < D) {
            float s = red[0 * D + tid] + red[1 * D + tid]
                    + red[2 * D + tid] + red[3 * D + tid];
            unsafeAtomicAdd(&acc_out[tid], s);
        }
    }
}

// ---------------------------------------------------------------------------
// Final: acc[64] -> mean -> [64] @ Wc[64,2] + bc -> out[2]
// ---------------------------------------------------------------------------
__global__ void final_kernel(const float* __restrict__ acc,
                             const float* __restrict__ Wc, const float* __restrict__ bc,
                             float* __restrict__ out, float invN)
{
    const int lane = threadIdx.x;  // 64 threads
    float m  = acc[lane] * invN;
    float o0 = m * Wc[lane * 2 + 0];
    float o1 = m * Wc[lane * 2 + 1];
#pragma unroll
    for (int off = 32; off > 0; off >>= 1) {
        o0 += __shfl_down(o0, off);
        o1 += __shfl_down(o1, off);
    }
    if (lane == 0) {
        out[0] = o0 + bc[0];
        out[1] = o1 + bc[1];
    }
}

extern "C" void kernel_launch(void* const* d_in, const int* in_sizes, int n_in,
                              void* d_out, int out_size, void* d_ws, size_t ws_size,
                              hipStream_t stream)
{
    const float* x       = (const float*)d_in[0];
    const void*  eidx    = d_in[1];
    const float* W1_rel  = (const float*)d_in[2];
    const float* W1_root = (const float*)d_in[3];
    const float* b1      = (const float*)d_in[4];
    const float* W2_rel  = (const float*)d_in[5];
    const float* W2_root = (const float*)d_in[6];
    const float* b2      = (const float*)d_in[7];
    const float* Wc      = (const float*)d_in[8];
    const float* bc      = (const float*)d_in[9];
    float* out = (float*)d_out;

    const int N = in_sizes[0] / D;
    const int E = in_sizes[1] / 2;

    auto align256 = [](size_t v) { return (v + 255) & ~(size_t)255; };

    char* p = (char*)d_ws;
    const size_t featBytes = align256((size_t)N * D * sizeof(float));
    float* aggr   = (float*)p; p += featBytes;
    float* h1     = (float*)p; p += featBytes;
    float* acc    = (float*)p; p += align256((size_t)D * sizeof(float));
    int*   count  = (int*)p;   p += align256((size_t)N * sizeof(int));
    int*   offs   = (int*)p;   p += align256(((size_t)N + 1) * sizeof(int));
    int*   bsum   = (int*)p;   p += align256((size_t)1024 * sizeof(int));
    int*   gbcur  = (int*)p;   p += align256((size_t)NBMAX * sizeof(int));
    int*   ssrc   = (int*)p;   p += align256((size_t)E * sizeof(int));
    uint2* ebuk   = (uint2*)p; p += align256((size_t)E * sizeof(uint2));
    int*   flag   = (int*)p;

    const int eblocks = (E + 255) / 256;
    const int nblk    = (N + 255) / 256;   // scan blocks (must be <= 1024)
    const int nbk     = (N + 255) >> 8;    // buckets of 256 nodes (= nblk)
    const int cblocks = (E + CHUNK - 1) / CHUNK;
    const int ltiles  = (N + ROWTILE - 1) / ROWTILE;
    const int lblocks = (ltiles + TPB_TILES - 1) / TPB_TILES;

    // ---- CSR build (once, reused by both layers) ----
    detect_kernel<<<1, 64, 0, stream>>>(eidx, flag);
    hipMemsetAsync(count, 0, (size_t)N * sizeof(int), stream);
    hipMemsetAsync(acc, 0, (size_t)D * sizeof(float), stream);
    hipMemsetAsync(gbcur, 0, (size_t)NBMAX * sizeof(int), stream);
    hist_kernel<<<eblocks, 256, 0, stream>>>(eidx, flag, count, E);
    scan1_kernel<<<nblk, 256, 0, stream>>>(count, offs, bsum, N);
    scan2_kernel<<<1, 1024, 0, stream>>>(bsum, nblk);
    scan3_kernel<<<nblk, 256, 0, stream>>>(offs, bsum, N, E);
    bucket_scatter_kernel<<<cblocks, 256, 0, stream>>>(
        eidx, flag, offs, gbcur, ebuk, E, N, nbk);
    bucket_csr_kernel<<<nbk, 256, 0, stream>>>(ebuk, offs, ssrc, N);

    const int ablocks = (N + 15) / 16;

    // ---- layer 1 ----
    gather_aggr_kernel<<<ablocks, 256, 0, stream>>>(x, ssrc, offs, aggr, N);
    linear_relu_kernel<true, false><<<lblocks, 256, 0, stream>>>(
        x, aggr, W1_rel, W1_root, b1, h1, nullptr, N, ltiles);

    // ---- layer 2 ----
    gather_aggr_kernel<<<ablocks, 256, 0, stream>>>(h1, ssrc, offs, aggr, N);
    linear_relu_kernel<false, true><<<lblocks, 256, 0, stream>>>(
        h1, aggr, W2_rel, W2_root, b2, nullptr, acc, N, ltiles);

    // ---- head ----
    final_kernel<<<1, 64, 0, stream>>>(acc, Wc, bc, out, 1.0f / (float)N);
}